// Round 1
// baseline (49.218 us; speedup 1.0000x reference)
//
#include <hip/hip_runtime.h>

// similarity[r] = sum_a (pp[r,a] - ph[a])^2 over a in [0,32); output = min_r similarity[r]
// pp: [R, 32] fp32 row-major, ph: [32] fp32, out: 1 fp32 scalar.

__global__ void doa_init_out(unsigned int* out) {
    // +inf bit pattern; fp32 sums of squares are >= 0, so uint ordering == float ordering
    *out = 0x7F800000u;
}

__global__ __launch_bounds__(256) void doa_min_kernel(
    const float* __restrict__ pp,
    const float* __restrict__ ph,
    unsigned int* __restrict__ out,
    int R)
{
    const int tid = blockIdx.x * blockDim.x + threadIdx.x;
    const int sub = tid & 7;               // which float4 of the row this lane owns
    const int row0 = tid >> 3;
    const int rstride = (gridDim.x * blockDim.x) >> 3;

    // broadcast phases chunk for this lane (128 B total, L1/L2 resident)
    const float4 phv = reinterpret_cast<const float4*>(ph)[sub];

    float lmin = __builtin_inff();

    for (int r = row0; r < R; r += rstride) {
        // rows are 32 floats = 128 B; 8 consecutive lanes read 8 consecutive float4s
        // -> each wave load instruction covers 1 KB contiguous
        const float4 p = reinterpret_cast<const float4*>(pp + (size_t)r * 32)[sub];
        const float dx = p.x - phv.x;
        const float dy = p.y - phv.y;
        const float dz = p.z - phv.z;
        const float dw = p.w - phv.w;
        float s = dx * dx + dy * dy + dz * dz + dw * dw;
        // sum the 8 partial sums of this row (8-lane butterfly)
        s += __shfl_xor(s, 1);
        s += __shfl_xor(s, 2);
        s += __shfl_xor(s, 4);
        lmin = fminf(lmin, s);
    }

    // wave-level min (lanes within an 8-group already hold identical values)
    lmin = fminf(lmin, __shfl_xor(lmin, 8));
    lmin = fminf(lmin, __shfl_xor(lmin, 16));
    lmin = fminf(lmin, __shfl_xor(lmin, 32));

    // block-level min across the 4 waves, then one atomic per block
    __shared__ float wmin[4];
    const int lane = threadIdx.x & 63;
    const int wid = threadIdx.x >> 6;
    if (lane == 0) wmin[wid] = lmin;
    __syncthreads();
    if (threadIdx.x == 0) {
        const float m = fminf(fminf(wmin[0], wmin[1]), fminf(wmin[2], wmin[3]));
        atomicMin(out, __float_as_uint(m));
    }
}

extern "C" void kernel_launch(void* const* d_in, const int* in_sizes, int n_in,
                              void* d_out, int out_size, void* d_ws, size_t ws_size,
                              hipStream_t stream) {
    const float* pp = (const float*)d_in[0];   // possible_phases [R, 32]
    const float* ph = (const float*)d_in[1];   // phases [32]
    unsigned int* out = (unsigned int*)d_out;  // 1 fp32 scalar

    const int R = in_sizes[0] / 32;

    doa_init_out<<<1, 1, 0, stream>>>(out);

    // memory-bound: cap grid, grid-stride the rest (Guideline 11)
    const int block = 256;
    const int grid = 2048;
    doa_min_kernel<<<grid, block, 0, stream>>>(pp, ph, out, R);
}